// Round 1
// 172.210 us; speedup vs baseline: 1.0088x; 1.0088x over previous
//
#include <hip/hip_runtime.h>

#define N_NODES 50000
#define IN_FEAT 512
#define OUT_FEAT 256
#define N_EDGES 1600000
#define ALPHA 0.2f

typedef float v4f __attribute__((ext_vector_type(4)));
typedef int   v4i __attribute__((ext_vector_type(4)));

// Kernel 1: fold W into the attention vectors (tiny: 512x256x2 MACs).
// w_src[i] = sum_j W[i][j]*attn_w[j];  w_tgt[i] = sum_j W[i][j]*attn_w[OUT_FEAT+j]
// One wave per row; lane l covers columns [4l,4l+4).
__global__ void fold_w_kernel(const float* __restrict__ W,
                              const float* __restrict__ attn_w,
                              float* __restrict__ w_src,
                              float* __restrict__ w_tgt) {
    int row  = (blockIdx.x * blockDim.x + threadIdx.x) >> 6;
    int lane = threadIdx.x & 63;
    if (row >= IN_FEAT) return;
    const v4f wv = *(const v4f*)(W + (size_t)row * OUT_FEAT + lane * 4);
    const v4f as = *(const v4f*)(attn_w + lane * 4);
    const v4f at = *(const v4f*)(attn_w + OUT_FEAT + lane * 4);
    float ssum = wv.x * as.x + wv.y * as.y + wv.z * as.z + wv.w * as.w;
    float tsum = wv.x * at.x + wv.y * at.y + wv.z * at.z + wv.w * at.w;
    #pragma unroll
    for (int off = 32; off > 0; off >>= 1) {
        ssum += __shfl_down(ssum, off, 64);
        tsum += __shfl_down(tsum, off, 64);
    }
    if (lane == 0) {
        w_src[row] = ssum;
        w_tgt[row] = tsum;
    }
}

// Kernel 2: per-node scores, TWO nodes per wave.
// s_src[n] = h[n,:].w_src ; s_tgt[n] = h[n,:].w_tgt
// Lane l reads 8 contiguous floats of each of the two rows (4x float4 NT loads
// in flight per wave -> better MLP; h is 102 MB streamed once, keep out of L2).
// w vectors (2 KB total) stay hot in cache.
__global__ void node_scores_kernel(const float* __restrict__ h,
                                   const float* __restrict__ w_src,
                                   const float* __restrict__ w_tgt,
                                   float* __restrict__ s_src,
                                   float* __restrict__ s_tgt) {
    int wid  = (blockIdx.x * blockDim.x + threadIdx.x) >> 6;
    int lane = threadIdx.x & 63;
    int n0 = wid * 2;
    if (n0 >= N_NODES) return;
    const v4f* r0 = (const v4f*)(h + (size_t)n0 * IN_FEAT + lane * 8);
    const v4f* r1 = (const v4f*)(h + (size_t)(n0 + 1) * IN_FEAT + lane * 8);
    const v4f a0 = __builtin_nontemporal_load(r0);
    const v4f a1 = __builtin_nontemporal_load(r0 + 1);
    const v4f b0 = __builtin_nontemporal_load(r1);
    const v4f b1 = __builtin_nontemporal_load(r1 + 1);
    const v4f ws0 = *(const v4f*)(w_src + lane * 8);
    const v4f ws1 = *(const v4f*)(w_src + lane * 8 + 4);
    const v4f wt0 = *(const v4f*)(w_tgt + lane * 8);
    const v4f wt1 = *(const v4f*)(w_tgt + lane * 8 + 4);

    float s0 = a0.x*ws0.x + a0.y*ws0.y + a0.z*ws0.z + a0.w*ws0.w
             + a1.x*ws1.x + a1.y*ws1.y + a1.z*ws1.z + a1.w*ws1.w;
    float t0 = a0.x*wt0.x + a0.y*wt0.y + a0.z*wt0.z + a0.w*wt0.w
             + a1.x*wt1.x + a1.y*wt1.y + a1.z*wt1.z + a1.w*wt1.w;
    float s1 = b0.x*ws0.x + b0.y*ws0.y + b0.z*ws0.z + b0.w*ws0.w
             + b1.x*ws1.x + b1.y*ws1.y + b1.z*ws1.z + b1.w*ws1.w;
    float t1 = b0.x*wt0.x + b0.y*wt0.y + b0.z*wt0.z + b0.w*wt0.w
             + b1.x*wt1.x + b1.y*wt1.y + b1.z*wt1.z + b1.w*wt1.w;

    #pragma unroll
    for (int off = 32; off > 0; off >>= 1) {
        s0 += __shfl_down(s0, off, 64);
        t0 += __shfl_down(t0, off, 64);
        s1 += __shfl_down(s1, off, 64);
        t1 += __shfl_down(t1, off, 64);
    }
    if (lane == 0) {
        s_src[n0]     = s0;
        s_tgt[n0]     = t0;
        s_src[n0 + 1] = s1;
        s_tgt[n0 + 1] = t1;
    }
}

// Kernel 3: per-edge gather + leaky_relu. 4 edges per thread (2x the waves of
// the 8-edge version -> better latency hiding on the random L2 gathers, which
// are ~full cache-line divergent). Edge list / out are streaming
// (non-temporal); score arrays (2x200KB) stay resident in L2.
__global__ void edge_kernel(const int* __restrict__ el,
                            const float* __restrict__ s_src,
                            const float* __restrict__ s_tgt,
                            float* __restrict__ out) {
    int i = blockIdx.x * blockDim.x + threadIdx.x;
    int base = i * 4;
    if (base >= N_EDGES) return;
    v4i src = __builtin_nontemporal_load((const v4i*)(el + base));
    v4i tgt = __builtin_nontemporal_load((const v4i*)(el + N_EDGES + base));
    v4f r;
    float v;
    // leaky_relu(v) = max(v, ALPHA*v) for 0 < ALPHA < 1 (one mul + one max)
    v = s_src[src.x] + s_tgt[tgt.x]; r.x = fmaxf(v, ALPHA * v);
    v = s_src[src.y] + s_tgt[tgt.y]; r.y = fmaxf(v, ALPHA * v);
    v = s_src[src.z] + s_tgt[tgt.z]; r.z = fmaxf(v, ALPHA * v);
    v = s_src[src.w] + s_tgt[tgt.w]; r.w = fmaxf(v, ALPHA * v);
    __builtin_nontemporal_store(r, (v4f*)(out + base));
}

extern "C" void kernel_launch(void* const* d_in, const int* in_sizes, int n_in,
                              void* d_out, int out_size, void* d_ws, size_t ws_size,
                              hipStream_t stream) {
    const float* h      = (const float*)d_in[0];
    const int*   el     = (const int*)d_in[1];   // int inputs arrive as int32
    const float* W      = (const float*)d_in[2];
    const float* attn_w = (const float*)d_in[3];
    float* out = (float*)d_out;

    // Workspace (floats): [0,512) w_src | [512,1024) w_tgt | [1024,51024) s_src | [51024,101024) s_tgt
    float* ws_f   = (float*)d_ws;
    float* w_src  = ws_f;
    float* w_tgt  = ws_f + IN_FEAT;
    float* s_src  = ws_f + 2 * IN_FEAT;
    float* s_tgt  = ws_f + 2 * IN_FEAT + N_NODES;

    // Kernel 1: 512 rows, one wave each -> 128 blocks of 256
    fold_w_kernel<<<(IN_FEAT * 64) / 256, 256, 0, stream>>>(W, attn_w, w_src, w_tgt);

    // Kernel 2: 50000 nodes, 2 per wave -> 25000 waves -> 6250 blocks
    node_scores_kernel<<<(N_NODES / 2 * 64) / 256, 256, 0, stream>>>(h, w_src, w_tgt, s_src, s_tgt);

    // Kernel 3: 1.6M edges, 4 per thread -> 400000 threads -> 1563 blocks
    edge_kernel<<<(N_EDGES / 4 + 255) / 256, 256, 0, stream>>>(el, s_src, s_tgt, out);
}